// Round 6
// baseline (244.581 us; speedup 1.0000x reference)
//
#include <hip/hip_runtime.h>
#include <hip/hip_bf16.h>
#include <math.h>

#define N_IN 85680
#define PRE_K 5000
#define POST_K 750
#define NW 79            // ceil(PRE_K/64) words
#define NPAD 5056        // NW*64
#define STR 80           // mask row stride in u64 (79 used, 1 pad)
#define HSIZE 8192       // linear buckets over score-bit range (0.02, +inf)
#define CAND_MAX 8192
#define CONF_THR 0.02f
#define NMS_THR 0.4f
#define BITS_THR 0x3CA3D70Bu  // bits of smallest float > 0.02f
#define NSLOT 96         // LDS row slots for propagation (96 KB)
#define G 4              // words per reduce group
#define NG ((NW + G - 1) / G)

typedef unsigned int u32;
typedef unsigned long long u64;

// opacity barrier: prevents FMA contraction so f32 math bit-matches numpy ref
__device__ __forceinline__ float opaquef(float x) { asm volatile("" : "+v"(x)); return x; }

// wave-uniform 64-bit broadcast via v_readlane (src lane must be uniform)
__device__ __forceinline__ u64 readlane64(u64 v, int l) {
    u32 lo = __builtin_amdgcn_readlane((u32)v, l);
    u32 hi = __builtin_amdgcn_readlane((u32)(v >> 32), l);
    return ((u64)hi << 32) | (u64)lo;
}

// monotone bucket of a score's float bits (score > CONF_THR guaranteed)
__device__ __forceinline__ u32 bucket_of(u32 bits) {
    u32 b = (bits - BITS_THR) >> 13;
    return b >= HSIZE ? (HSIZE - 1) : b;
}

// async global->LDS 16B: global src is PER-LANE, LDS dest is wave-uniform base
// (HW writes base + lane*16)
__device__ __forceinline__ void gload_lds16(const void* g, void* l) {
    __builtin_amdgcn_global_load_lds(
        (const __attribute__((address_space(1))) void*)g,
        (__attribute__((address_space(3))) void*)l, 16, 0, 0);
}

// ---------------- histogram of valid score buckets ----------------
__global__ __launch_bounds__(256) void hist_kernel(const float2* __restrict__ conf2,
                                                   u32* __restrict__ hist) {
    __shared__ u32 h[HSIZE];
    for (int b = threadIdx.x; b < HSIZE; b += 256) h[b] = 0u;
    __syncthreads();
    int i = blockIdx.x * 256 + threadIdx.x;
    if (i < N_IN) {
        float s = conf2[i].y;
        if (s > CONF_THR) atomicAdd(&h[bucket_of(__float_as_uint(s))], 1u);
    }
    __syncthreads();
    for (int b = threadIdx.x; b < HSIZE; b += 256) {
        u32 v = h[b];
        if (v) atomicAdd(&hist[b], v);
    }
}

// ---------------- suffix-scan: bstart[b] = #keys in buckets > b; bsel ----------------
__global__ __launch_bounds__(1024) void scan_kernel(const u32* __restrict__ hist,
                                                    u32* __restrict__ bsel,
                                                    u32* __restrict__ bstart) {
    __shared__ u32 tot[1024];
    int c = threadIdx.x;
    u32 lh[8];
    u32 t = 0;
#pragma unroll
    for (int k = 0; k < 8; ++k) { lh[k] = hist[c * 8 + k]; t += lh[k]; }
    tot[c] = t;
    __syncthreads();
    for (int d = 1; d < 1024; d <<= 1) {
        u32 v = tot[c] + ((c + d < 1024) ? tot[c + d] : 0u);
        __syncthreads();
        tot[c] = v;
        __syncthreads();
    }
    u32 above = (c + 1 < 1024) ? tot[c + 1] : 0u;  // suffix starting at next chunk
    // exclusive suffix starts for this thread's 8 buckets
    u32 s = above;
    for (int k = 7; k >= 0; --k) { bstart[c * 8 + k] = s; s += lh[k]; }
    // bsel = max bucket with inclusive-suffix >= PRE_K (boundary thread unique)
    if (above < PRE_K && above + t >= PRE_K) {
        u32 cum = above;
        for (int k = 7; k >= 0; --k) {
            cum += lh[k];
            if (cum >= PRE_K) { bsel[0] = (u32)(c * 8 + k); break; }
        }
    }
    if (c == 0 && tot[0] < PRE_K) bsel[0] = 0u;   // fewer than PRE_K valid: take all
}

// ---------------- scatter candidates bucket-grouped ----------------
__global__ __launch_bounds__(256) void compact_kernel(const float2* __restrict__ conf2,
                                                      const u32* __restrict__ bsel,
                                                      const u32* __restrict__ bstart,
                                                      u32* __restrict__ bfill,
                                                      u64* __restrict__ cand) {
    int i = blockIdx.x * 256 + threadIdx.x;
    if (i >= N_IN) return;
    float sc = conf2[i].y;
    if (!(sc > CONF_THR)) return;
    u32 bits = __float_as_uint(sc);
    u32 b = bucket_of(bits);
    if (b < bsel[0]) return;
    u32 pos = bstart[b] + atomicAdd(&bfill[b], 1u);
    // key: high = score bits, low = ~i  (greater key == higher score, then lower index)
    if (pos < CAND_MAX) cand[pos] = ((u64)bits << 32) | (u64)(u32)(~(u32)i);
}

// ---------------- fused: exact rank within bucket + decode -> rows/boxes/validm ----------------
__global__ __launch_bounds__(256) void rankdec_kernel(const u64* __restrict__ cand,
                                                      const u32* __restrict__ bstart,
                                                      const u32* __restrict__ bfill,
                                                      const u32* __restrict__ bsel,
                                                      const float4* __restrict__ loc4,
                                                      const float4* __restrict__ pri4,
                                                      const float* __restrict__ lmk,
                                                      const int* __restrict__ imw,
                                                      const int* __restrict__ imh,
                                                      float4* __restrict__ rows4,
                                                      float4* __restrict__ boxes,
                                                      u64* __restrict__ validm) {
    u32 bs = bsel[0];
    u32 total = bstart[bs] + bfill[bs];
    if (total > CAND_MAX) total = CAND_MAX;
    float W = (float)(*imw), H = (float)(*imh);
    for (u32 s = blockIdx.x * blockDim.x + threadIdx.x; s < total;
         s += gridDim.x * blockDim.x) {
        u64 key = cand[s];
        u32 b = bucket_of((u32)(key >> 32));
        u32 st = bstart[b];
        u32 en = st + bfill[b];
        if (en > CAND_MAX) en = CAND_MAX;
        u32 r = st;
        for (u32 j = st; j < en; ++j) r += (cand[j] > key) ? 1u : 0u;
        if (r >= PRE_K) continue;
        u32 i = ~(u32)key;
        float score = __uint_as_float((u32)(key >> 32));
        float4 L = loc4[i];
        float4 P = pri4[i];
        float cx = P.x + opaquef((L.x * 0.1f) * P.z);
        float cy = P.y + opaquef((L.y * 0.1f) * P.w);
        // exp in f64 then round: ~correctly-rounded f32 exp (closest to numpy)
        float bw = P.z * (float)exp((double)(L.z * 0.2f));
        float bh = P.w * (float)exp((double)(L.w * 0.2f));
        float hw = opaquef(bw * 0.5f), hh = opaquef(bh * 0.5f);
        float x0 = (cx - hw) * W, y0 = (cy - hh) * H;
        float x1 = (cx + hw) * W, y1 = (cy + hh) * H;
        boxes[r] = make_float4(x0, y0, x1, y1);
        float lm[10];
#pragma unroll
        for (int p = 0; p < 5; ++p) {
            float2 q = ((const float2*)lmk)[(size_t)i * 5 + p];
            lm[2 * p]     = (P.x + opaquef((q.x * 0.1f) * P.z)) * W;
            lm[2 * p + 1] = (P.y + opaquef((q.y * 0.1f) * P.w)) * H;
        }
        float4* row = rows4 + (size_t)r * 4;
        row[0] = make_float4(x0, y0, x1, y1);
        row[1] = make_float4(score, lm[0], lm[1], lm[2]);
        row[2] = make_float4(lm[3], lm[4], lm[5], lm[6]);
        row[3] = make_float4(lm[7], lm[8], lm[9], 0.f);
        atomicOr(&validm[r >> 6], 1ull << (r & 63));
    }
}

// ---------------- pairwise IoU suppression bitmask (flat triangular grid) ----------------
__global__ __launch_bounds__(64) void mask_kernel(const float4* __restrict__ boxes,
                                                  u64* __restrict__ mask) {
    // flat bid -> (rc, cc) with cc >= rc; row rc owns NW-rc blocks
    int rem = blockIdx.x, rc = 0;
    while (rem >= NW - rc) { rem -= NW - rc; ++rc; }
    int cc = rc + rem;
    __shared__ float4 cb[64];
    int t = threadIdx.x;
    cb[t] = boxes[cc * 64 + t];
    int i = rc * 64 + t;
    float4 bi = boxes[i];
    __syncthreads();
    float areai = (bi.z - bi.x) * (bi.w - bi.y);
    u64 word = 0ull;
    int jbase = cc * 64;
#pragma unroll 4
    for (int k = 0; k < 64; ++k) {
        float4 bj = cb[k];
        float areaj = (bj.z - bj.x) * (bj.w - bj.y);
        float ltx = fmaxf(bi.x, bj.x), lty = fmaxf(bi.y, bj.y);
        float rbx = fminf(bi.z, bj.z), rby = fminf(bi.w, bj.w);
        float wx = fmaxf(rbx - ltx, 0.f), wy = fmaxf(rby - lty, 0.f);
        float inter = opaquef(wx * wy);
        float uni = fmaxf(areai + areaj - inter, 1e-12f);
        float iou = inter / uni;
        if ((jbase + k) > i && iou > NMS_THR) word |= (1ull << k);
    }
    if (i < PRE_K) mask[(size_t)i * STR + cc] = word;  // rows >= PRE_K not allocated
}

// ---------------- single-wave greedy NMS reduce (v6: G=4 grouped) ----------------
//  - per group of 4 words: GxG diagonal block (rows of the 4 words x their 4
//    columns) gathered into 32 VGPRs ONE GROUP AHEAD; all in-group cross-word
//    suppression comes from registers via v_readlane (exact row bits)
//  - kept-row full-line DMAs (global_load_lds, 1KB/row) issued inside the chain;
//    ONE vmcnt(0) wait per GROUP, folded from LDS at next group start
//  - early exit once total kept >= POST_K
__global__ __launch_bounds__(64) void reduce_kernel(const u64* __restrict__ mask,
                                                    const u64* __restrict__ validm,
                                                    u64* __restrict__ keepw) {
    int lane = threadIdx.x;
    __shared__ __align__(16) u64 prop[NSLOT * 128];  // 96 row slots x 1 KiB

    u64 remv0 = 0ull, remv1 = 0ull, keep0 = 0ull, keep1 = 0ull;
    u64 valid0 = validm[lane];
    bool lo2 = (lane < NW - 64);
    u64 valid1 = lo2 ? validm[64 + lane] : 0ull;
    u32 total = 0;
    int k = 0, kprev = 0;

    u64 dc[G][G], dn[G][G];
    // prologue: gather group 0 diag block (lane b holds rows s*64+b, cols 0..3)
#pragma unroll
    for (int s = 0; s < G; ++s) {
        int r = s * 64 + lane;
        const u64* p = mask + (size_t)r * STR;  // w0 = 0
        ulonglong2 a = *(const ulonglong2*)p;
        ulonglong2 bq = *(const ulonglong2*)(p + 2);
        dc[s][0] = a.x; dc[s][1] = a.y; dc[s][2] = bq.x; dc[s][3] = bq.y;
    }

    for (int grp = 0; grp < NG; ++grp) {
        int w0 = grp * G;
        // drain this group's diag gather + prev group's row DMAs
        asm volatile("s_waitcnt vmcnt(0)" ::: "memory");
        __builtin_amdgcn_sched_barrier(0);
        // issue next group's diag-block gather (covered by this group's chain)
        if (grp + 1 < NG) {
            int w0n = w0 + G;
#pragma unroll
            for (int s = 0; s < G; ++s) {
                int r = (w0n + s) * 64 + lane;
                if (r > PRE_K - 1) r = PRE_K - 1;   // clamp: rows >= 5000 unused
                const u64* p = mask + (size_t)r * STR + w0n;
                ulonglong2 a = *(const ulonglong2*)p;
                ulonglong2 bq = *(const ulonglong2*)(p + 2);
                dn[s][0] = a.x; dn[s][1] = a.y; dn[s][2] = bq.x; dn[s][3] = bq.y;
            }
        }
        // fold previous group's kept rows from LDS into remv
        for (int j = 0; j < kprev; ++j) {
            remv0 |= prop[j * 128 + lane];
            if (lo2) remv1 |= prop[j * 128 + 64 + lane];
        }
        __builtin_amdgcn_sched_barrier(0);

        k = 0;
        u64 acc1 = 0ull, acc2 = 0ull, acc3 = 0ull;  // in-group column contributions
#pragma unroll
        for (int g = 0; g < G; ++g) {
            int w = w0 + g;
            if (w >= NW) break;
            u64 remw, valw;
            if (w < 64) { remw = readlane64(remv0, w); valw = readlane64(valid0, w); }
            else        { remw = readlane64(remv1, w - 64); valw = readlane64(valid1, w - 64); }
            if (g == 1) remw |= acc1;
            if (g == 2) remw |= acc2;
            if (g == 3) remw |= acc3;
            u64 cur = valw & ~remw;            // wave-uniform
            u64 keptw = 0ull;
            while (cur) {
                int b = __ffsll(cur) - 1;
                keptw |= (1ull << b);
                int row = (w << 6) + b;
                if (k < NSLOT) {               // full-row DMA for cross-group fold
                    gload_lds16((const char*)(mask + (size_t)row * STR) + lane * 16,
                                (void*)(prop + (size_t)k * 128));
                    ++k;
                } else {                        // pathological overflow: direct fold
                    const u64* rp = mask + (size_t)row * STR;
                    remv0 |= rp[lane];
                    if (lo2) remv1 |= rp[64 + lane];
                }
                if (g < 1) acc1 |= readlane64(dc[0][1], b);
                if (g < 2) acc2 |= readlane64(dc[g][2], b);
                if (g < 3) acc3 |= readlane64(dc[g][3], b);
                u64 roww = readlane64(dc[g][g], b);  // same-word suppression bits
                cur &= ~(roww | (1ull << b));
            }
            if (w < 64) { if (lane == w) keep0 |= keptw; }
            else if (lane == w - 64) keep1 |= keptw;
            total += (u32)__popcll(keptw);
            if (total >= POST_K) goto done;    // output fully determined
        }
        kprev = (k < NSLOT) ? k : NSLOT;
        // rotate diag-block buffers (register copies)
#pragma unroll
        for (int s = 0; s < G; ++s)
#pragma unroll
            for (int c = 0; c < G; ++c) dc[s][c] = dn[s][c];
    }
done:
    keepw[lane] = keep0;
    keepw[64 + lane] = keep1;
}

// ---------------- scatter kept rows (rank < POST_K) + zero-fill tail ----------------
__global__ __launch_bounds__(256) void scatter_kernel(const float* __restrict__ rows,
                                                      const u64* __restrict__ keepw,
                                                      float* __restrict__ out) {
    int r = blockIdx.x * 256 + threadIdx.x;
    if (r >= PRE_K) return;
    int w = r >> 6, b = r & 63;
    u64 kw = keepw[w];
    bool kept = (kw >> b) & 1ull;
    if (kept) {
        u32 rank = (u32)__popcll(kw & ((1ull << b) - 1ull));
        for (int u = 0; u < w; ++u) rank += (u32)__popcll(keepw[u]);  // L1-cached 640B
        if (rank < POST_K) {
            const float* src = rows + (size_t)r * 16;
            float* dst = out + (size_t)rank * 15;
#pragma unroll
            for (int c = 0; c < 15; ++c) dst[c] = src[c];
        }
    }
    if (r < POST_K) {  // zero-fill ranks never produced (out is not pre-zeroed)
        u32 totk = 0;
        for (int u = 0; u < NW; ++u) totk += (u32)__popcll(keepw[u]);
        if ((u32)r >= totk) {
            float* dst = out + (size_t)r * 15;
#pragma unroll
            for (int c = 0; c < 15; ++c) dst[c] = 0.f;
        }
    }
}

extern "C" void kernel_launch(void* const* d_in, const int* in_sizes, int n_in,
                              void* d_out, int out_size, void* d_ws, size_t ws_size,
                              hipStream_t stream) {
    const float* loc = (const float*)d_in[0];
    const float2* conf2 = (const float2*)d_in[1];
    const float* lmk = (const float*)d_in[2];
    const float* pri = (const float*)d_in[3];
    const int* imw = (const int*)d_in[4];
    const int* imh = (const int*)d_in[5];
    float* out = (float*)d_out;
    char* base = (char*)d_ws;

    // workspace layout (bytes); total 3,767,232 (< 3,808,896 proven in R3-R5)
    u32* hist   = (u32*)(base + 0);         //  32768  [zeroed]
    u32* bfill  = (u32*)(base + 32768);     //  32768  [zeroed]
    u32* bsel   = (u32*)(base + 65536);     //  64     [zeroed]
    u64* validm = (u64*)(base + 65600);     //  1024   [zeroed]   -> zero [0,66624)
    u64* keepw  = (u64*)(base + 66624);     //  1024   (fully written by reduce)
    u32* bstart = (u32*)(base + 67648);     //  32768
    u64* cand   = (u64*)(base + 100416);    //  65536
    float* rows = (float*)(base + 165952);  //  320000 (5000 x 16)
    float4* boxes = (float4*)(base + 485952); // 80896 (NPAD x 16; pads read-garbage-OK)
    u64* mask   = (u64*)(base + 566848);    //  3200384 (PRE_K x STR x 8 + 1KB overrun)

    hipMemsetAsync(d_ws, 0, 66624, stream);

    hist_kernel<<<(N_IN + 255) / 256, 256, 0, stream>>>(conf2, hist);
    scan_kernel<<<1, 1024, 0, stream>>>(hist, bsel, bstart);
    compact_kernel<<<(N_IN + 255) / 256, 256, 0, stream>>>(conf2, bsel, bstart, bfill, cand);
    rankdec_kernel<<<24, 256, 0, stream>>>(cand, bstart, bfill, bsel, (const float4*)loc,
                                           (const float4*)pri, lmk, imw, imh,
                                           (float4*)rows, boxes, validm);
    mask_kernel<<<NW * (NW + 1) / 2, 64, 0, stream>>>(boxes, mask);
    reduce_kernel<<<1, 64, 0, stream>>>(mask, validm, keepw);
    scatter_kernel<<<(PRE_K + 255) / 256, 256, 0, stream>>>(rows, keepw, out);
}

// Round 7
// 204.473 us; speedup vs baseline: 1.1961x; 1.1961x over previous
//
#include <hip/hip_runtime.h>
#include <hip/hip_bf16.h>
#include <math.h>

#define N_IN 85680
#define PRE_K 5000
#define POST_K 750
#define NW 79            // ceil(PRE_K/64) words
#define NPAD 5056        // NW*64
#define STR 80           // mask row stride in u64 (79 used, 1 pad)
#define HSIZE 8192       // linear buckets over score-bit range (0.02, +inf)
#define CAND_MAX 8192
#define CONF_THR 0.02f
#define NMS_THR 0.4f
#define BITS_THR 0x3CA3D70Bu  // bits of smallest float > 0.02f
#define KMAX 24          // row-DMA slots issued per word (STATIC count)
// per-word vmcnt allowance = KMAX DMAs(w-1) + 2 diag(w+1) = 26  (hardcoded below)

typedef unsigned int u32;
typedef unsigned long long u64;

// opacity barrier: prevents FMA contraction so f32 math bit-matches numpy ref
__device__ __forceinline__ float opaquef(float x) { asm volatile("" : "+v"(x)); return x; }

// wave-uniform 64-bit broadcast via v_readlane (src lane must be uniform)
__device__ __forceinline__ u64 readlane64(u64 v, int l) {
    u32 lo = __builtin_amdgcn_readlane((u32)v, l);
    u32 hi = __builtin_amdgcn_readlane((u32)(v >> 32), l);
    return ((u64)hi << 32) | (u64)lo;
}

// monotone bucket of a score's float bits (score > CONF_THR guaranteed)
__device__ __forceinline__ u32 bucket_of(u32 bits) {
    u32 b = (bits - BITS_THR) >> 13;
    return b >= HSIZE ? (HSIZE - 1) : b;
}

// async global->LDS 16B: global src is PER-LANE, LDS dest is wave-uniform base
// (HW writes base + lane*16)
__device__ __forceinline__ void gload_lds16(const void* g, void* l) {
    __builtin_amdgcn_global_load_lds(
        (const __attribute__((address_space(1))) void*)g,
        (__attribute__((address_space(3))) void*)l, 16, 0, 0);
}

// ---------------- histogram of valid score buckets ----------------
__global__ __launch_bounds__(256) void hist_kernel(const float2* __restrict__ conf2,
                                                   u32* __restrict__ hist) {
    __shared__ u32 h[HSIZE];
    for (int b = threadIdx.x; b < HSIZE; b += 256) h[b] = 0u;
    __syncthreads();
    int i = blockIdx.x * 256 + threadIdx.x;
    if (i < N_IN) {
        float s = conf2[i].y;
        if (s > CONF_THR) atomicAdd(&h[bucket_of(__float_as_uint(s))], 1u);
    }
    __syncthreads();
    for (int b = threadIdx.x; b < HSIZE; b += 256) {
        u32 v = h[b];
        if (v) atomicAdd(&hist[b], v);
    }
}

// ---------------- suffix-scan: bstart[b] = #keys in buckets > b; bsel ----------------
__global__ __launch_bounds__(1024) void scan_kernel(const u32* __restrict__ hist,
                                                    u32* __restrict__ bsel,
                                                    u32* __restrict__ bstart) {
    __shared__ u32 tot[1024];
    int c = threadIdx.x;
    u32 lh[8];
    u32 t = 0;
#pragma unroll
    for (int k = 0; k < 8; ++k) { lh[k] = hist[c * 8 + k]; t += lh[k]; }
    tot[c] = t;
    __syncthreads();
    for (int d = 1; d < 1024; d <<= 1) {
        u32 v = tot[c] + ((c + d < 1024) ? tot[c + d] : 0u);
        __syncthreads();
        tot[c] = v;
        __syncthreads();
    }
    u32 above = (c + 1 < 1024) ? tot[c + 1] : 0u;  // suffix starting at next chunk
    // exclusive suffix starts for this thread's 8 buckets
    u32 s = above;
    for (int k = 7; k >= 0; --k) { bstart[c * 8 + k] = s; s += lh[k]; }
    // bsel = max bucket with inclusive-suffix >= PRE_K (boundary thread unique)
    if (above < PRE_K && above + t >= PRE_K) {
        u32 cum = above;
        for (int k = 7; k >= 0; --k) {
            cum += lh[k];
            if (cum >= PRE_K) { bsel[0] = (u32)(c * 8 + k); break; }
        }
    }
    if (c == 0 && tot[0] < PRE_K) bsel[0] = 0u;   // fewer than PRE_K valid: take all
}

// ---------------- scatter candidates bucket-grouped ----------------
__global__ __launch_bounds__(256) void compact_kernel(const float2* __restrict__ conf2,
                                                      const u32* __restrict__ bsel,
                                                      const u32* __restrict__ bstart,
                                                      u32* __restrict__ bfill,
                                                      u64* __restrict__ cand) {
    int i = blockIdx.x * 256 + threadIdx.x;
    if (i >= N_IN) return;
    float sc = conf2[i].y;
    if (!(sc > CONF_THR)) return;
    u32 bits = __float_as_uint(sc);
    u32 b = bucket_of(bits);
    if (b < bsel[0]) return;
    u32 pos = bstart[b] + atomicAdd(&bfill[b], 1u);
    // key: high = score bits, low = ~i  (greater key == higher score, then lower index)
    if (pos < CAND_MAX) cand[pos] = ((u64)bits << 32) | (u64)(u32)(~(u32)i);
}

// ---------------- fused: exact rank within bucket + decode -> rows/boxes/validm ----------------
__global__ __launch_bounds__(256) void rankdec_kernel(const u64* __restrict__ cand,
                                                      const u32* __restrict__ bstart,
                                                      const u32* __restrict__ bfill,
                                                      const u32* __restrict__ bsel,
                                                      const float4* __restrict__ loc4,
                                                      const float4* __restrict__ pri4,
                                                      const float* __restrict__ lmk,
                                                      const int* __restrict__ imw,
                                                      const int* __restrict__ imh,
                                                      float4* __restrict__ rows4,
                                                      float4* __restrict__ boxes,
                                                      u64* __restrict__ validm) {
    u32 bs = bsel[0];
    u32 total = bstart[bs] + bfill[bs];
    if (total > CAND_MAX) total = CAND_MAX;
    float W = (float)(*imw), H = (float)(*imh);
    for (u32 s = blockIdx.x * blockDim.x + threadIdx.x; s < total;
         s += gridDim.x * blockDim.x) {
        u64 key = cand[s];
        u32 b = bucket_of((u32)(key >> 32));
        u32 st = bstart[b];
        u32 en = st + bfill[b];
        if (en > CAND_MAX) en = CAND_MAX;
        u32 r = st;
        for (u32 j = st; j < en; ++j) r += (cand[j] > key) ? 1u : 0u;
        if (r >= PRE_K) continue;
        u32 i = ~(u32)key;
        float score = __uint_as_float((u32)(key >> 32));
        float4 L = loc4[i];
        float4 P = pri4[i];
        float cx = P.x + opaquef((L.x * 0.1f) * P.z);
        float cy = P.y + opaquef((L.y * 0.1f) * P.w);
        // exp in f64 then round: ~correctly-rounded f32 exp (closest to numpy)
        float bw = P.z * (float)exp((double)(L.z * 0.2f));
        float bh = P.w * (float)exp((double)(L.w * 0.2f));
        float hw = opaquef(bw * 0.5f), hh = opaquef(bh * 0.5f);
        float x0 = (cx - hw) * W, y0 = (cy - hh) * H;
        float x1 = (cx + hw) * W, y1 = (cy + hh) * H;
        boxes[r] = make_float4(x0, y0, x1, y1);
        float lm[10];
#pragma unroll
        for (int p = 0; p < 5; ++p) {
            float2 q = ((const float2*)lmk)[(size_t)i * 5 + p];
            lm[2 * p]     = (P.x + opaquef((q.x * 0.1f) * P.z)) * W;
            lm[2 * p + 1] = (P.y + opaquef((q.y * 0.1f) * P.w)) * H;
        }
        float4* row = rows4 + (size_t)r * 4;
        row[0] = make_float4(x0, y0, x1, y1);
        row[1] = make_float4(score, lm[0], lm[1], lm[2]);
        row[2] = make_float4(lm[3], lm[4], lm[5], lm[6]);
        row[3] = make_float4(lm[7], lm[8], lm[9], 0.f);
        atomicOr(&validm[r >> 6], 1ull << (r & 63));
    }
}

// ---------------- pairwise IoU suppression bitmask (flat triangular grid) ----------------
__global__ __launch_bounds__(64) void mask_kernel(const float4* __restrict__ boxes,
                                                  u64* __restrict__ mask) {
    // flat bid -> (rc, cc) with cc >= rc; row rc owns NW-rc blocks
    int rem = blockIdx.x, rc = 0;
    while (rem >= NW - rc) { rem -= NW - rc; ++rc; }
    int cc = rc + rem;
    __shared__ float4 cb[64];
    int t = threadIdx.x;
    cb[t] = boxes[cc * 64 + t];
    int i = rc * 64 + t;
    float4 bi = boxes[i];
    __syncthreads();
    float areai = (bi.z - bi.x) * (bi.w - bi.y);
    u64 word = 0ull;
    int jbase = cc * 64;
#pragma unroll 4
    for (int k = 0; k < 64; ++k) {
        float4 bj = cb[k];
        float areaj = (bj.z - bj.x) * (bj.w - bj.y);
        float ltx = fmaxf(bi.x, bj.x), lty = fmaxf(bi.y, bj.y);
        float rbx = fminf(bi.z, bj.z), rby = fminf(bi.w, bj.w);
        float wx = fmaxf(rbx - ltx, 0.f), wy = fmaxf(rby - lty, 0.f);
        float inter = opaquef(wx * wy);
        float uni = fmaxf(areai + areaj - inter, 1e-12f);
        float iou = inter / uni;
        if ((jbase + k) > i && iou > NMS_THR) word |= (1ull << k);
    }
    if (i < PRE_K) mask[(size_t)i * STR + cc] = word;  // rows >= PRE_K not allocated
}

// ---------------- single-wave greedy NMS reduce (v7: counted-vmcnt pipeline) ----------------
// Invariant: nothing consumed at word w was issued later than word w-2.
//  - diag pair (cols [w,w+1] of word-w rows) DMA'd at word w-2 into a 4-slot ring
//  - col w+1 bits (acc) let word w's keeps suppress word w+1 WITHOUT waiting
//    for their row DMAs; full rows folded with a 2-word lag
//  - exactly KMAX row-DMAs issued per word (dummy-padded) => static outstanding
//    count => one s_waitcnt vmcnt(26) per word that drains only 2-word-old ops
//  - early exit once total kept >= POST_K
__global__ __launch_bounds__(64) void reduce_kernel(const u64* __restrict__ mask,
                                                    const u64* __restrict__ validm,
                                                    u64* __restrict__ keepw) {
    int lane = threadIdx.x;
    __shared__ __align__(16) u64 prop[2][KMAX * 128];  // 48 KiB row slots, parity ring
    __shared__ __align__(16) u64 dbuf[4][2][128];      // 8 KiB diag ring (2x16B per word)

    u64 remv0 = 0ull, remv1 = 0ull, keep0 = 0ull, keep1 = 0ull;
    u64 valid0 = validm[lane];
    bool lo2 = (lane < NW - 64);
    u64 valid1 = lo2 ? validm[64 + lane] : 0ull;
    u32 total = 0;
    u64 acc = 0ull;           // col-w suppression from word w-1's kept boxes
    int kprev = 0, kprev2 = 0;

    // prologue: diag DMAs for words 0 and 1 (B = w & ~1 = 0 for both)
    {
        const u64* p0 = mask + (size_t)lane * STR;
        gload_lds16(p0,     &dbuf[0][0][0]);
        gload_lds16(p0 + 2, &dbuf[0][1][0]);
        const u64* p1 = mask + (size_t)(64 + lane) * STR;
        gload_lds16(p1,     &dbuf[1][0][0]);
        gload_lds16(p1 + 2, &dbuf[1][1][0]);
    }

    for (int w = 0; w < NW; ++w) {
        // counted wait: allow newest [KMAX DMAs(w-1) + 2 diag(w+1)] to stay in flight
        if (w == 0) { asm volatile("s_waitcnt vmcnt(2)" ::: "memory"); }
        else        { asm volatile("s_waitcnt vmcnt(26)" ::: "memory"); }  // = KMAX+2
        __builtin_amdgcn_sched_barrier(0);

        // this word's diag from LDS ring (written at w-2, drained above)
        int rb = w & 3;
        u64 d_cur = dbuf[rb][0][lane * 2 + (w & 1)];                       // col w
        u64 d_nxt = (w & 1) ? dbuf[rb][1][lane * 2] : dbuf[rb][0][lane * 2 + 1];  // col w+1

        // fold word w-2's kept rows (their DMAs drained above)
        u64* pslab = prop[w & 1];
        for (int j = 0; j < kprev2; ++j) {
            remv0 |= pslab[j * 128 + lane];
            if (lo2) remv1 |= pslab[j * 128 + 64 + lane];
        }
        __builtin_amdgcn_sched_barrier(0);

        // issue diag DMAs for word w+2 (ALWAYS 2, for static accounting; tail = dummy)
        {
            int u = (w + 2 < NW) ? (w + 2) : (NW - 1);
            int row = u * 64 + lane; if (row > PRE_K - 1) row = PRE_K - 1;
            const u64* p = mask + (size_t)row * STR + (u & ~1);
            gload_lds16(p,     &dbuf[(w + 2) & 3][0][0]);
            gload_lds16(p + 2, &dbuf[(w + 2) & 3][1][0]);
        }

        // decide word w
        u64 remw, valw;
        if (w < 64) { remw = readlane64(remv0, w); valw = readlane64(valid0, w); }
        else        { remw = readlane64(remv1, w - 64); valw = readlane64(valid1, w - 64); }
        remw |= acc;
        u64 cur = valw & ~remw;            // wave-uniform
        u64 keptw = 0ull, accn = 0ull;
        int kreal = 0;
        const char* wbase = (const char*)(mask + ((size_t)w << 6) * STR);
        while (cur) {
            int b = __ffsll(cur) - 1;
            keptw |= (1ull << b);
            if (kreal < KMAX) {            // row DMA for the 2-word-lag fold
                gload_lds16(wbase + (size_t)b * (STR * 8) + lane * 16,
                            &pslab[kreal * 128]);
                ++kreal;
            } else {                       // rare overflow: direct fold (drains pipe)
                const u64* rp = mask + (size_t)((w << 6) + b) * STR;
                remv0 |= rp[lane];
                if (lo2) remv1 |= rp[64 + lane];
            }
            accn |= readlane64(d_nxt, b);  // suppress word w+1 via in-reg col w+1
            u64 roww = readlane64(d_cur, b);
            cur &= ~(roww | (1ull << b));
        }
        for (int kk = kreal; kk < KMAX; ++kk)   // dummy-pad to static KMAX
            gload_lds16(wbase + lane * 16, &pslab[kk * 128]);

        if (w < 64) { if (lane == w) keep0 |= keptw; }
        else if (lane == w - 64) keep1 |= keptw;
        total += (u32)__popcll(keptw);
        if (total >= POST_K) break;        // output fully determined
        acc = accn;
        kprev2 = kprev;
        kprev = kreal;
    }

    // drain in-flight DMAs before workgroup teardown (LDS dealloc safety)
    asm volatile("s_waitcnt vmcnt(0)" ::: "memory");
    keepw[lane] = keep0;
    keepw[64 + lane] = keep1;
}

// ---------------- scatter kept rows (rank < POST_K) + zero-fill tail ----------------
__global__ __launch_bounds__(256) void scatter_kernel(const float* __restrict__ rows,
                                                      const u64* __restrict__ keepw,
                                                      float* __restrict__ out) {
    int r = blockIdx.x * 256 + threadIdx.x;
    if (r >= PRE_K) return;
    int w = r >> 6, b = r & 63;
    u64 kw = keepw[w];
    bool kept = (kw >> b) & 1ull;
    if (kept) {
        u32 rank = (u32)__popcll(kw & ((1ull << b) - 1ull));
        for (int u = 0; u < w; ++u) rank += (u32)__popcll(keepw[u]);  // L1-cached 640B
        if (rank < POST_K) {
            const float* src = rows + (size_t)r * 16;
            float* dst = out + (size_t)rank * 15;
#pragma unroll
            for (int c = 0; c < 15; ++c) dst[c] = src[c];
        }
    }
    if (r < POST_K) {  // zero-fill ranks never produced (out is not pre-zeroed)
        u32 totk = 0;
        for (int u = 0; u < NW; ++u) totk += (u32)__popcll(keepw[u]);
        if ((u32)r >= totk) {
            float* dst = out + (size_t)r * 15;
#pragma unroll
            for (int c = 0; c < 15; ++c) dst[c] = 0.f;
        }
    }
}

extern "C" void kernel_launch(void* const* d_in, const int* in_sizes, int n_in,
                              void* d_out, int out_size, void* d_ws, size_t ws_size,
                              hipStream_t stream) {
    const float* loc = (const float*)d_in[0];
    const float2* conf2 = (const float2*)d_in[1];
    const float* lmk = (const float*)d_in[2];
    const float* pri = (const float*)d_in[3];
    const int* imw = (const int*)d_in[4];
    const int* imh = (const int*)d_in[5];
    float* out = (float*)d_out;
    char* base = (char*)d_ws;

    // workspace layout (bytes); total 3,767,232 (< 3,808,896 proven in R3-R6)
    u32* hist   = (u32*)(base + 0);         //  32768  [zeroed]
    u32* bfill  = (u32*)(base + 32768);     //  32768  [zeroed]
    u32* bsel   = (u32*)(base + 65536);     //  64     [zeroed]
    u64* validm = (u64*)(base + 65600);     //  1024   [zeroed]   -> zero [0,66624)
    u64* keepw  = (u64*)(base + 66624);     //  1024   (fully written by reduce)
    u32* bstart = (u32*)(base + 67648);     //  32768
    u64* cand   = (u64*)(base + 100416);    //  65536
    float* rows = (float*)(base + 165952);  //  320000 (5000 x 16)
    float4* boxes = (float4*)(base + 485952); // 80896 (NPAD x 16; pads read-garbage-OK)
    u64* mask   = (u64*)(base + 566848);    //  3200384 (PRE_K x STR x 8 + 1KB overrun)

    hipMemsetAsync(d_ws, 0, 66624, stream);

    hist_kernel<<<(N_IN + 255) / 256, 256, 0, stream>>>(conf2, hist);
    scan_kernel<<<1, 1024, 0, stream>>>(hist, bsel, bstart);
    compact_kernel<<<(N_IN + 255) / 256, 256, 0, stream>>>(conf2, bsel, bstart, bfill, cand);
    rankdec_kernel<<<24, 256, 0, stream>>>(cand, bstart, bfill, bsel, (const float4*)loc,
                                           (const float4*)pri, lmk, imw, imh,
                                           (float4*)rows, boxes, validm);
    mask_kernel<<<NW * (NW + 1) / 2, 64, 0, stream>>>(boxes, mask);
    reduce_kernel<<<1, 64, 0, stream>>>(mask, validm, keepw);
    scatter_kernel<<<(PRE_K + 255) / 256, 256, 0, stream>>>(rows, keepw, out);
}